// Round 2
// baseline (155.180 us; speedup 1.0000x reference)
//
#include <hip/hip_runtime.h>
#include <hip/hip_bf16.h>

#define NQ 6
#define DIM 64
#define NL 6

// ---------------------------------------------------------------------------
// Kernel 1: build circuit matrix C (column m = circuit|e_m>), one block.
// State S[buf][re/im][row][col] in LDS, double-buffered, 1 barrier per gate.
// Output: Cout[0..4095] = Re(C) row-major [k][m], Cout[4096..8191] = Im(C).
// ---------------------------------------------------------------------------
__global__ __launch_bounds__(1024) void build_C_kernel(const float* __restrict__ w,
                                                       float* __restrict__ Cout) {
    __shared__ float S[2][2][DIM][DIM];  // 64 KB
    const int tid = threadIdx.x;

    for (int e = tid; e < DIM * DIM; e += 1024) {
        int k = e >> 6, col = e & 63;
        S[0][0][k][col] = (k == col) ? 1.f : 0.f;
        S[0][1][k][col] = 0.f;
    }
    __syncthreads();

    int cur = 0;
    for (int l = 0; l < NL; ++l) {
        // --- single-qubit rotations: U00=ep*c U01=-conj(em)*s U10=em*s U11=conj(ep)*c
        for (int j = 0; j < NQ; ++j) {
            const int bw = (l * NQ + j) * 3;
            float phi = w[bw], theta = w[bw + 1], omega = w[bw + 2];
            float ch = cosf(0.5f * theta), sh = sinf(0.5f * theta);
            float ap = -0.5f * (phi + omega), am = -0.5f * (phi - omega);
            float epr = cosf(ap), epi = sinf(ap);
            float emr = cosf(am), emi = sinf(am);
            float u00r =  epr * ch, u00i =  epi * ch;
            float u01r = -emr * sh, u01i =  emi * sh;
            float u10r =  emr * sh, u10i =  emi * sh;
            float u11r =  epr * ch, u11i = -epi * ch;
            const int m = 1 << (5 - j);
            for (int e = tid; e < DIM * DIM; e += 1024) {
                int k = e >> 6, col = e & 63;
                int k0 = k & ~m, k1 = k | m;
                float a0r = S[cur][0][k0][col], a0i = S[cur][1][k0][col];
                float a1r = S[cur][0][k1][col], a1i = S[cur][1][k1][col];
                float nr, ni;
                if (k & m) {
                    nr = u10r * a0r - u10i * a0i + u11r * a1r - u11i * a1i;
                    ni = u10r * a0i + u10i * a0r + u11r * a1i + u11i * a1r;
                } else {
                    nr = u00r * a0r - u00i * a0i + u01r * a1r - u01i * a1i;
                    ni = u00r * a0i + u00i * a0r + u01r * a1i + u01i * a1r;
                }
                S[cur ^ 1][0][k][col] = nr;
                S[cur ^ 1][1][k][col] = ni;
            }
            cur ^= 1;
            __syncthreads();
        }
        // --- CNOT ring: new[k] = old[k ^ tm] if control bit set, else old[k]
        const int r = l % (NQ - 1) + 1;
        for (int j = 0; j < NQ; ++j) {
            const int cm = 1 << (5 - j);
            const int tm = 1 << (5 - ((j + r) % NQ));
            for (int e = tid; e < DIM * DIM; e += 1024) {
                int k = e >> 6, col = e & 63;
                int src = (k & cm) ? (k ^ tm) : k;
                S[cur ^ 1][0][k][col] = S[cur][0][src][col];
                S[cur ^ 1][1][k][col] = S[cur][1][src][col];
            }
            cur ^= 1;
            __syncthreads();
        }
    }

    for (int e = tid; e < DIM * DIM; e += 1024) {
        int k = e >> 6, m = e & 63;
        Cout[e]             = S[cur][0][k][m];
        Cout[DIM * DIM + e] = S[cur][1][k][m];
    }
}

// ---------------------------------------------------------------------------
// Kernel 2: per sample b: psi = product state (registers, compile-time
// indexed), y = C psi (complex matvec, C broadcast from LDS), p_k = |y_k|^2,
// out[b][j] = sum_k sign_j(k) p_k with sign_j from the SCALAR index k
// (SALU cselect -> SGPR operand, off the vector pipe).
// ---------------------------------------------------------------------------
__global__ __launch_bounds__(256) void qexp_kernel(const float* __restrict__ x,
                                                   const float* __restrict__ C,
                                                   float* __restrict__ out,
                                                   int batch) {
    __shared__ __align__(16) float Cr[DIM * DIM];
    __shared__ __align__(16) float Ci[DIM * DIM];
    for (int i = threadIdx.x; i < DIM * DIM; i += 256) {
        Cr[i] = C[i];
        Ci[i] = C[DIM * DIM + i];
    }
    __syncthreads();

    int b = blockIdx.x * 256 + threadIdx.x;
    if (b >= batch) return;

    // x row: 24B per sample, 8-byte aligned -> three float2 loads
    const float2* xp = (const float2*)(x + (size_t)b * NQ);
    float2 x01 = xp[0], x23 = xp[1], x45 = xp[2];
    float xa[NQ] = {x01.x, x01.y, x23.x, x23.y, x45.x, x45.y};

    float c[NQ], s[NQ];
    #pragma unroll
    for (int j = 0; j < NQ; ++j) {
        float ang = 1.57079632679489662f * xa[j];
        __sincosf(ang, &s[j], &c[j]);
    }

    // psi[idx]: qubit j contributes bit (5-j) (qubit 0 = MSB), matching the
    // reference's psi build (append qubit j as fastest-varying index).
    float psi[DIM];
    psi[0] = 1.f;
    #pragma unroll
    for (int j = 0; j < NQ; ++j) {
        #pragma unroll
        for (int i = (1 << j) - 1; i >= 0; --i) {
            float v = psi[i];
            psi[2 * i + 1] = v * s[j];
            psi[2 * i]     = v * c[j];
        }
    }

    float sm[NQ] = {0.f, 0.f, 0.f, 0.f, 0.f, 0.f};
    #pragma unroll 4
    for (int k = 0; k < DIM; ++k) {
        const float4* rr = (const float4*)&Cr[k << 6];
        const float4* ri = (const float4*)&Ci[k << 6];
        float yr0 = 0.f, yr1 = 0.f, yi0 = 0.f, yi1 = 0.f;
        #pragma unroll
        for (int q = 0; q < 16; ++q) {
            float4 ar = rr[q], ai = ri[q];
            yr0 = fmaf(ar.x, psi[4 * q + 0], yr0);
            yr1 = fmaf(ar.y, psi[4 * q + 1], yr1);
            yr0 = fmaf(ar.z, psi[4 * q + 2], yr0);
            yr1 = fmaf(ar.w, psi[4 * q + 3], yr1);
            yi0 = fmaf(ai.x, psi[4 * q + 0], yi0);
            yi1 = fmaf(ai.y, psi[4 * q + 1], yi1);
            yi0 = fmaf(ai.z, psi[4 * q + 2], yi0);
            yi1 = fmaf(ai.w, psi[4 * q + 3], yi1);
        }
        float yr = yr0 + yr1, yi = yi0 + yi1;
        float p = fmaf(yr, yr, yi * yi);
        #pragma unroll
        for (int j = 0; j < NQ; ++j) {
            // k is scalar (loop counter): sign resolves on the SALU
            float sg = ((k >> (5 - j)) & 1) ? -1.f : 1.f;
            sm[j] = fmaf(sg, p, sm[j]);
        }
    }

    float2* op = (float2*)(out + (size_t)b * NQ);
    op[0] = make_float2(sm[0], sm[1]);
    op[1] = make_float2(sm[2], sm[3]);
    op[2] = make_float2(sm[4], sm[5]);
}

extern "C" void kernel_launch(void* const* d_in, const int* in_sizes, int n_in,
                              void* d_out, int out_size, void* d_ws, size_t ws_size,
                              hipStream_t stream) {
    const float* x = (const float*)d_in[0];
    const float* w = (const float*)d_in[1];
    float* C   = (float*)d_ws;   // 8192 floats = 32 KB
    float* out = (float*)d_out;
    const int batch = in_sizes[0] / NQ;

    build_C_kernel<<<1, 1024, 0, stream>>>(w, C);
    const int blocks = (batch + 255) / 256;
    qexp_kernel<<<blocks, 256, 0, stream>>>(x, C, out, batch);
}

// Round 4
// 37.696 us; speedup vs baseline: 4.1166x; 4.1166x over previous
//
#include <hip/hip_runtime.h>
#include <hip/hip_bf16.h>

#define NQ 6
#define DIM 64
#define NL 6

typedef _Float16 half8 __attribute__((ext_vector_type(8)));
typedef float f32x4 __attribute__((ext_vector_type(4)));

// ---------------------------------------------------------------------------
// Kernel 1: build circuit matrix C, output packed f16.
// Cout dwords [0..2047] = Re(C)[k][m] as f16 pairs (m even in low half),
//            [2048..4095] = Im(C). Row-major, 32 dwords (64 f16) per row k.
// 1 block / 1024 threads. Trig precomputed once into LDS. Rotations run
// in-place (each thread owns whole butterfly pairs). CNOT ring fused into a
// single permutation step per layer -> 42 barriered steps total.
// ---------------------------------------------------------------------------
__global__ __launch_bounds__(1024) void build_C_kernel(const float* __restrict__ w,
                                                       unsigned* __restrict__ Cout) {
    __shared__ float Sr[2][DIM][DIM];   // 16 KB each buffer
    __shared__ float Si[2][DIM][DIM];
    __shared__ float trig[NL * NQ][3][2];
    const int tid = threadIdx.x;

    if (tid < NL * NQ * 3) {
        int g = tid / 3, q = tid - g * 3;
        float phi = w[g * 3], theta = w[g * 3 + 1], omega = w[g * 3 + 2];
        float a = (q == 0) ? 0.5f * theta
                           : (q == 1 ? -0.5f * (phi + omega) : -0.5f * (phi - omega));
        trig[g][q][0] = cosf(a);
        trig[g][q][1] = sinf(a);
    }
    for (int e = tid; e < DIM * DIM; e += 1024) {
        int k = e >> 6, col = e & 63;
        Sr[0][k][col] = (k == col) ? 1.f : 0.f;
        Si[0][k][col] = 0.f;
    }
    __syncthreads();

    int cur = 0;
    #pragma unroll
    for (int l = 0; l < NL; ++l) {
        #pragma unroll
        for (int j = 0; j < NQ; ++j) {
            const int g = l * NQ + j;
            float ch = trig[g][0][0], sh = trig[g][0][1];
            float epr = trig[g][1][0], epi = trig[g][1][1];
            float emr = trig[g][2][0], emi = trig[g][2][1];
            float u00r =  epr * ch, u00i =  epi * ch;
            float u01r = -emr * sh, u01i =  emi * sh;
            float u10r =  emr * sh, u10i =  emi * sh;
            float u11r =  epr * ch, u11i = -epi * ch;
            const int m = 1 << (5 - j);
            const int lowm = m - 1;
            #pragma unroll
            for (int pp = 0; pp < 2; ++pp) {
                int p = tid + pp * 1024;            // 2048 butterfly pairs
                int col = p & 63, pr = p >> 6;
                int row0 = ((pr & ~lowm) << 1) | (pr & lowm);
                int row1 = row0 | m;
                float a0r = Sr[cur][row0][col], a0i = Si[cur][row0][col];
                float a1r = Sr[cur][row1][col], a1i = Si[cur][row1][col];
                Sr[cur][row0][col] = u00r * a0r - u00i * a0i + u01r * a1r - u01i * a1i;
                Si[cur][row0][col] = u00r * a0i + u00i * a0r + u01r * a1i + u01i * a1r;
                Sr[cur][row1][col] = u10r * a0r - u10i * a0i + u11r * a1r - u11i * a1i;
                Si[cur][row1][col] = u10r * a0i + u10i * a0r + u11r * a1i + u11i * a1r;
            }
            __syncthreads();
        }
        // fused CNOT-ring permutation: src = f0(f1(...f5(k)...))
        const int r = l % (NQ - 1) + 1;
        #pragma unroll
        for (int ee = 0; ee < 4; ++ee) {
            int e = tid + ee * 1024;
            int k = e >> 6, col = e & 63;
            int src = k;
            #pragma unroll
            for (int jj = NQ - 1; jj >= 0; --jj) {
                int cm = 1 << (5 - jj);
                int tm = 1 << (5 - ((jj + r) % NQ));
                src = (src & cm) ? (src ^ tm) : src;
            }
            Sr[cur ^ 1][k][col] = Sr[cur][src][col];
            Si[cur ^ 1][k][col] = Si[cur][src][col];
        }
        cur ^= 1;
        __syncthreads();
    }

    for (int d = tid; d < DIM * DIM / 2; d += 1024) {
        int k = d >> 5, mp = d & 31;
        Cout[d] = __builtin_bit_cast(unsigned,
            __builtin_amdgcn_cvt_pkrtz(Sr[cur][k][2 * mp], Sr[cur][k][2 * mp + 1]));
        Cout[DIM * DIM / 2 + d] = __builtin_bit_cast(unsigned,
            __builtin_amdgcn_cvt_pkrtz(Si[cur][k][2 * mp], Si[cur][k][2 * mp + 1]));
    }
}

// ---------------------------------------------------------------------------
// Kernel 2: MFMA. Per wave: 64 samples. Phase 1: each lane builds psi (f16)
// for its sample into LDS (padded stride 36 dwords -> 2-way banks, free).
// Phase 2: 4 groups x 16 samples: Y = C*Psi via mfma_f32_16x16x32_f16
// (8 MFMA per K-step: 4 k-tiles x {Re,Im}); epilogue p=|y|^2 with signs from
// compile-time bits (ktile, reg) + 2 per-lane XOR masks; shfl_xor reduce.
// A/B frags both packed with the same contiguous k-map (k = g*8+2r+h) ->
// result is layout-invariant; only the verified D layout is relied upon.
// ---------------------------------------------------------------------------
__global__ __launch_bounds__(256) void qexp_mfma(const float* __restrict__ x,
                                                 const unsigned* __restrict__ C,
                                                 float* __restrict__ out,
                                                 int batch) {
    __shared__ __align__(16) unsigned Psi[256 * 36];  // 36 KB, 144 B/row
    const int tid  = threadIdx.x;
    const int lane = tid & 63;
    const int wave = tid >> 6;
    const int n    = lane & 15;
    const int g    = lane >> 4;
    const int sbase = blockIdx.x * 256 + wave * 64;

    // ---- persistent A-frags: C matrix, 16 frags (4 ktiles x 2 ksteps x Re/Im)
    half8 Ar[4][2], Ai[4][2];
    #pragma unroll
    for (int t = 0; t < 4; ++t)
        #pragma unroll
        for (int s = 0; s < 2; ++s) {
            int dw = (t * 16 + n) * 32 + s * 16 + g * 4;
            Ar[t][s] = __builtin_bit_cast(half8, *(const int4*)(C + dw));
            Ai[t][s] = __builtin_bit_cast(half8, *(const int4*)(C + 2048 + dw));
        }

    // ---- psi for sample sbase+lane, f16-packed into LDS row tid
    {
        const float2* xp = (const float2*)(x + (size_t)(sbase + lane) * NQ);
        float2 x01 = xp[0], x23 = xp[1], x45 = xp[2];
        float xa[6] = {x01.x, x01.y, x23.x, x23.y, x45.x, x45.y};
        float cs[6], sn[6];
        #pragma unroll
        for (int j = 0; j < 6; ++j) {
            float a = 1.57079632679489662f * xa[j];
            __sincosf(a, &sn[j], &cs[j]);
        }
        float a00 = cs[0] * cs[1], a01 = cs[0] * sn[1];
        float a10 = sn[0] * cs[1], a11 = sn[0] * sn[1];
        float hi[8] = {a00 * cs[2], a00 * sn[2], a01 * cs[2], a01 * sn[2],
                       a10 * cs[2], a10 * sn[2], a11 * cs[2], a11 * sn[2]};
        float b00 = cs[3] * cs[4], b01 = cs[3] * sn[4];
        float b10 = sn[3] * cs[4], b11 = sn[3] * sn[4];
        float lo[8] = {b00 * cs[5], b00 * sn[5], b01 * cs[5], b01 * sn[5],
                       b10 * cs[5], b10 * sn[5], b11 * cs[5], b11 * sn[5]};
        const int rowbase = tid * 36;
        #pragma unroll
        for (int c = 0; c < 8; ++c) {
            float h = hi[c];
            int4 d;
            d.x = __builtin_bit_cast(int, __builtin_amdgcn_cvt_pkrtz(h * lo[0], h * lo[1]));
            d.y = __builtin_bit_cast(int, __builtin_amdgcn_cvt_pkrtz(h * lo[2], h * lo[3]));
            d.z = __builtin_bit_cast(int, __builtin_amdgcn_cvt_pkrtz(h * lo[4], h * lo[5]));
            d.w = __builtin_bit_cast(int, __builtin_amdgcn_cvt_pkrtz(h * lo[6], h * lo[7]));
            *(int4*)(&Psi[rowbase + c * 4]) = d;
        }
    }
    __syncthreads();

    const unsigned m2 = (unsigned)(g >> 1) << 31;   // k_out bit3 mask (j=2)
    const unsigned m3 = (unsigned)(g & 1) << 31;    // k_out bit2 mask (j=3)

    #pragma unroll
    for (int grp = 0; grp < 4; ++grp) {
        f32x4 accr[4], acci[4];
        #pragma unroll
        for (int t = 0; t < 4; ++t) { accr[t] = (f32x4)0.f; acci[t] = (f32x4)0.f; }

        #pragma unroll
        for (int s = 0; s < 2; ++s) {
            int bd = (wave * 64 + grp * 16 + n) * 36 + s * 16 + g * 4;
            half8 B = __builtin_bit_cast(half8, *(const int4*)(&Psi[bd]));
            #pragma unroll
            for (int t = 0; t < 4; ++t) {
                accr[t] = __builtin_amdgcn_mfma_f32_16x16x32_f16(Ar[t][s], B, accr[t], 0, 0, 0);
                acci[t] = __builtin_amdgcn_mfma_f32_16x16x32_f16(Ai[t][s], B, acci[t], 0, 0, 0);
            }
        }

        float o0 = 0.f, o1 = 0.f, o2 = 0.f, o3 = 0.f, o4 = 0.f, o5 = 0.f;
        #pragma unroll
        for (int t = 0; t < 4; ++t) {
            #pragma unroll
            for (int i = 0; i < 4; ++i) {
                // k_out = t*16 + g*4 + i ; D layout: col=n, row=g*4+i (verified)
                float yr = accr[t][i], yi = acci[t][i];
                float p = fmaf(yr, yr, yi * yi);
                if (t & 2) o0 -= p; else o0 += p;      // j=0 <- bit5 (compile-time)
                if (t & 1) o1 -= p; else o1 += p;      // j=1 <- bit4 (compile-time)
                o2 += __builtin_bit_cast(float, __builtin_bit_cast(unsigned, p) ^ m2);
                o3 += __builtin_bit_cast(float, __builtin_bit_cast(unsigned, p) ^ m3);
                if (i & 2) o4 -= p; else o4 += p;      // j=4 <- bit1 (compile-time)
                if (i & 1) o5 -= p; else o5 += p;      // j=5 <- bit0 (compile-time)
            }
        }
        // fold the 4 k-groups (lanes n, n+16, n+32, n+48)
        o0 += __shfl_xor(o0, 16); o0 += __shfl_xor(o0, 32);
        o1 += __shfl_xor(o1, 16); o1 += __shfl_xor(o1, 32);
        o2 += __shfl_xor(o2, 16); o2 += __shfl_xor(o2, 32);
        o3 += __shfl_xor(o3, 16); o3 += __shfl_xor(o3, 32);
        o4 += __shfl_xor(o4, 16); o4 += __shfl_xor(o4, 32);
        o5 += __shfl_xor(o5, 16); o5 += __shfl_xor(o5, 32);

        int sample = sbase + grp * 16 + n;
        float2* op = (float2*)(out + (size_t)sample * 6);
        if (g == 0)      op[0] = make_float2(o0, o1);
        else if (g == 1) op[1] = make_float2(o2, o3);
        else if (g == 2) op[2] = make_float2(o4, o5);
    }
}

extern "C" void kernel_launch(void* const* d_in, const int* in_sizes, int n_in,
                              void* d_out, int out_size, void* d_ws, size_t ws_size,
                              hipStream_t stream) {
    const float* x = (const float*)d_in[0];
    const float* w = (const float*)d_in[1];
    unsigned* C = (unsigned*)d_ws;   // 4096 dwords = 16 KB (f16-packed Re|Im)
    float* out = (float*)d_out;
    const int batch = in_sizes[0] / NQ;

    build_C_kernel<<<1, 1024, 0, stream>>>(w, C);
    const int blocks = (batch + 255) / 256;   // 1024 blocks x 256 threads
    qexp_mfma<<<blocks, 256, 0, stream>>>(x, C, out, batch);
}

// Round 5
// 23.006 us; speedup vs baseline: 6.7452x; 1.6385x over previous
//
#include <hip/hip_runtime.h>
#include <hip/hip_bf16.h>

#define NQ 6
#define DIM 64
#define NL 6

typedef _Float16 half8 __attribute__((ext_vector_type(8)));
typedef float f32x4 __attribute__((ext_vector_type(4)));

// ---------------------------------------------------------------------------
// Kernel 1 (v3): one WAVE per column of C; lane k holds amplitude k in 2
// VGPRs. Rotation gate = 2x shfl_xor + 8 FMA + 4 selects; fused CNOT-ring
// permutation = 2x shfl with per-lane src (same composition as the verified
// v2). Gate coefficients computed once by threads 0..35 into LDS (one
// barrier), read wave-uniformly. 16 blocks x 256 threads = 64 waves.
// Output: same packed-f16 layout as before — u16[k*64+m] = Re(C[k][m]),
// u16[4096 + k*64+m] = Im(C[k][m]).
// ---------------------------------------------------------------------------
__global__ __launch_bounds__(256) void build_C_kernel(const float* __restrict__ w,
                                                      unsigned short* __restrict__ Cu) {
    __shared__ __align__(16) float Uc[NL * NQ][8];
    const int tid  = threadIdx.x;
    const int lane = tid & 63;
    const int wave = tid >> 6;
    const int col  = blockIdx.x * 4 + wave;

    if (tid < NL * NQ) {
        float phi = w[3 * tid], th = w[3 * tid + 1], om = w[3 * tid + 2];
        float ch = cosf(0.5f * th), sh = sinf(0.5f * th);
        float ap = -0.5f * (phi + om), am = -0.5f * (phi - om);
        float epr = cosf(ap), epi = sinf(ap);
        float emr = cosf(am), emi = sinf(am);
        Uc[tid][0] =  epr * ch;  // u00r
        Uc[tid][1] =  epi * ch;  // u00i
        Uc[tid][2] = -emr * sh;  // u01r
        Uc[tid][3] =  emi * sh;  // u01i
        Uc[tid][4] =  emr * sh;  // u10r
        Uc[tid][5] =  emi * sh;  // u10i
        Uc[tid][6] =  epr * ch;  // u11r
        Uc[tid][7] = -epi * ch;  // u11i
    }
    __syncthreads();

    float re = (lane == col) ? 1.f : 0.f;
    float im = 0.f;

    #pragma unroll
    for (int l = 0; l < NL; ++l) {
        #pragma unroll
        for (int j = 0; j < NQ; ++j) {
            const int g = l * NQ + j;
            const int m = 1 << (5 - j);
            float4 uA = *(const float4*)&Uc[g][0];  // u00r u00i u01r u01i
            float4 uB = *(const float4*)&Uc[g][4];  // u10r u10i u11r u11i
            float pr = __shfl_xor(re, m);
            float pi = __shfl_xor(im, m);
            const bool hi = (lane & m) != 0;
            float Ar = hi ? uB.z : uA.x;
            float Ai = hi ? uB.w : uA.y;
            float Br = hi ? uB.x : uA.z;
            float Bi = hi ? uB.y : uA.w;
            float nr = Ar * re - Ai * im + Br * pr - Bi * pi;
            float ni = Ar * im + Ai * re + Br * pi + Bi * pr;
            re = nr; im = ni;
        }
        // fused CNOT-ring permutation: new[k] = old[src(k)]
        const int r = l % (NQ - 1) + 1;
        int src = lane;
        #pragma unroll
        for (int jj = NQ - 1; jj >= 0; --jj) {
            int cm = 1 << (5 - jj);
            int tm = 1 << (5 - ((jj + r) % NQ));
            src = (src & cm) ? (src ^ tm) : src;
        }
        re = __shfl(re, src);
        im = __shfl(im, src);
    }

    // scattered one-time f16 stores: lane k writes C[k][col]
    _Float16 hr = (_Float16)re, hi16 = (_Float16)im;
    Cu[lane * 64 + col]        = __builtin_bit_cast(unsigned short, hr);
    Cu[4096 + lane * 64 + col] = __builtin_bit_cast(unsigned short, hi16);
}

// ---------------------------------------------------------------------------
// Kernel 2: MFMA. Per wave: 64 samples. Phase 1: each lane builds psi (f16)
// for its sample into LDS (padded stride 36 dwords -> 2-way banks, free).
// Phase 2: 4 groups x 16 samples: Y = C*Psi via mfma_f32_16x16x32_f16
// (8 MFMA per K-step: 4 k-tiles x {Re,Im}); epilogue p=|y|^2 with signs from
// compile-time bits (ktile, reg) + 2 per-lane XOR masks; shfl_xor reduce.
// A/B frags both packed with the same contiguous k-map -> layout-invariant;
// only the verified D layout (col=lane&15, row=g*4+reg) is relied upon.
// ---------------------------------------------------------------------------
__global__ __launch_bounds__(256) void qexp_mfma(const float* __restrict__ x,
                                                 const unsigned* __restrict__ C,
                                                 float* __restrict__ out,
                                                 int batch) {
    __shared__ __align__(16) unsigned Psi[256 * 36];  // 36 KB, 144 B/row
    const int tid  = threadIdx.x;
    const int lane = tid & 63;
    const int wave = tid >> 6;
    const int n    = lane & 15;
    const int g    = lane >> 4;
    const int sbase = blockIdx.x * 256 + wave * 64;

    // ---- persistent A-frags: C matrix, 16 frags (4 ktiles x 2 ksteps x Re/Im)
    half8 Ar[4][2], Ai[4][2];
    #pragma unroll
    for (int t = 0; t < 4; ++t)
        #pragma unroll
        for (int s = 0; s < 2; ++s) {
            int dw = (t * 16 + n) * 32 + s * 16 + g * 4;
            Ar[t][s] = __builtin_bit_cast(half8, *(const int4*)(C + dw));
            Ai[t][s] = __builtin_bit_cast(half8, *(const int4*)(C + 2048 + dw));
        }

    // ---- psi for sample sbase+lane, f16-packed into LDS row tid
    {
        const float2* xp = (const float2*)(x + (size_t)(sbase + lane) * NQ);
        float2 x01 = xp[0], x23 = xp[1], x45 = xp[2];
        float xa[6] = {x01.x, x01.y, x23.x, x23.y, x45.x, x45.y};
        float cs[6], sn[6];
        #pragma unroll
        for (int j = 0; j < 6; ++j) {
            float a = 1.57079632679489662f * xa[j];
            __sincosf(a, &sn[j], &cs[j]);
        }
        float a00 = cs[0] * cs[1], a01 = cs[0] * sn[1];
        float a10 = sn[0] * cs[1], a11 = sn[0] * sn[1];
        float hi[8] = {a00 * cs[2], a00 * sn[2], a01 * cs[2], a01 * sn[2],
                       a10 * cs[2], a10 * sn[2], a11 * cs[2], a11 * sn[2]};
        float b00 = cs[3] * cs[4], b01 = cs[3] * sn[4];
        float b10 = sn[3] * cs[4], b11 = sn[3] * sn[4];
        float lo[8] = {b00 * cs[5], b00 * sn[5], b01 * cs[5], b01 * sn[5],
                       b10 * cs[5], b10 * sn[5], b11 * cs[5], b11 * sn[5]};
        const int rowbase = tid * 36;
        #pragma unroll
        for (int c = 0; c < 8; ++c) {
            float h = hi[c];
            int4 d;
            d.x = __builtin_bit_cast(int, __builtin_amdgcn_cvt_pkrtz(h * lo[0], h * lo[1]));
            d.y = __builtin_bit_cast(int, __builtin_amdgcn_cvt_pkrtz(h * lo[2], h * lo[3]));
            d.z = __builtin_bit_cast(int, __builtin_amdgcn_cvt_pkrtz(h * lo[4], h * lo[5]));
            d.w = __builtin_bit_cast(int, __builtin_amdgcn_cvt_pkrtz(h * lo[6], h * lo[7]));
            *(int4*)(&Psi[rowbase + c * 4]) = d;
        }
    }
    __syncthreads();

    const unsigned m2 = (unsigned)(g >> 1) << 31;   // k_out bit3 mask (j=2)
    const unsigned m3 = (unsigned)(g & 1) << 31;    // k_out bit2 mask (j=3)

    #pragma unroll
    for (int grp = 0; grp < 4; ++grp) {
        f32x4 accr[4], acci[4];
        #pragma unroll
        for (int t = 0; t < 4; ++t) { accr[t] = (f32x4)0.f; acci[t] = (f32x4)0.f; }

        #pragma unroll
        for (int s = 0; s < 2; ++s) {
            int bd = (wave * 64 + grp * 16 + n) * 36 + s * 16 + g * 4;
            half8 B = __builtin_bit_cast(half8, *(const int4*)(&Psi[bd]));
            #pragma unroll
            for (int t = 0; t < 4; ++t) {
                accr[t] = __builtin_amdgcn_mfma_f32_16x16x32_f16(Ar[t][s], B, accr[t], 0, 0, 0);
                acci[t] = __builtin_amdgcn_mfma_f32_16x16x32_f16(Ai[t][s], B, acci[t], 0, 0, 0);
            }
        }

        float o0 = 0.f, o1 = 0.f, o2 = 0.f, o3 = 0.f, o4 = 0.f, o5 = 0.f;
        #pragma unroll
        for (int t = 0; t < 4; ++t) {
            #pragma unroll
            for (int i = 0; i < 4; ++i) {
                // k_out = t*16 + g*4 + i ; D layout: col=n, row=g*4+i (verified)
                float yr = accr[t][i], yi = acci[t][i];
                float p = fmaf(yr, yr, yi * yi);
                if (t & 2) o0 -= p; else o0 += p;      // j=0 <- bit5 (compile-time)
                if (t & 1) o1 -= p; else o1 += p;      // j=1 <- bit4 (compile-time)
                o2 += __builtin_bit_cast(float, __builtin_bit_cast(unsigned, p) ^ m2);
                o3 += __builtin_bit_cast(float, __builtin_bit_cast(unsigned, p) ^ m3);
                if (i & 2) o4 -= p; else o4 += p;      // j=4 <- bit1 (compile-time)
                if (i & 1) o5 -= p; else o5 += p;      // j=5 <- bit0 (compile-time)
            }
        }
        // fold the 4 k-groups (lanes n, n+16, n+32, n+48)
        o0 += __shfl_xor(o0, 16); o0 += __shfl_xor(o0, 32);
        o1 += __shfl_xor(o1, 16); o1 += __shfl_xor(o1, 32);
        o2 += __shfl_xor(o2, 16); o2 += __shfl_xor(o2, 32);
        o3 += __shfl_xor(o3, 16); o3 += __shfl_xor(o3, 32);
        o4 += __shfl_xor(o4, 16); o4 += __shfl_xor(o4, 32);
        o5 += __shfl_xor(o5, 16); o5 += __shfl_xor(o5, 32);

        int sample = sbase + grp * 16 + n;
        float2* op = (float2*)(out + (size_t)sample * 6);
        if (g == 0)      op[0] = make_float2(o0, o1);
        else if (g == 1) op[1] = make_float2(o2, o3);
        else if (g == 2) op[2] = make_float2(o4, o5);
    }
}

extern "C" void kernel_launch(void* const* d_in, const int* in_sizes, int n_in,
                              void* d_out, int out_size, void* d_ws, size_t ws_size,
                              hipStream_t stream) {
    const float* x = (const float*)d_in[0];
    const float* w = (const float*)d_in[1];
    unsigned* C = (unsigned*)d_ws;   // 4096 dwords = 16 KB (f16-packed Re|Im)
    float* out = (float*)d_out;
    const int batch = in_sizes[0] / NQ;

    build_C_kernel<<<16, 256, 0, stream>>>(w, (unsigned short*)C);
    const int blocks = (batch + 255) / 256;   // 1024 blocks x 256 threads
    qexp_mfma<<<blocks, 256, 0, stream>>>(x, C, out, batch);
}

// Round 6
// 21.211 us; speedup vs baseline: 7.3159x; 1.0846x over previous
//
#include <hip/hip_runtime.h>
#include <hip/hip_bf16.h>

#define NQ 6
#define DIM 64
#define NL 6

typedef _Float16 half8 __attribute__((ext_vector_type(8)));
typedef float f32x4 __attribute__((ext_vector_type(4)));

// ---------------------------------------------------------------------------
// Kernel 1 (v3): one WAVE per column of C; lane k holds amplitude k in 2
// VGPRs. Rotation gate = 2x shfl_xor + 8 FMA + 4 selects; fused CNOT-ring
// permutation = 2x shfl with per-lane src. Gate coefficients computed once
// by threads 0..35 into LDS (one barrier), read wave-uniformly.
// Output: u16[k*64+m] = Re(C[k][m]) f16, u16[4096 + k*64+m] = Im(C[k][m]).
// ---------------------------------------------------------------------------
__global__ __launch_bounds__(256) void build_C_kernel(const float* __restrict__ w,
                                                      unsigned short* __restrict__ Cu) {
    __shared__ __align__(16) float Uc[NL * NQ][8];
    const int tid  = threadIdx.x;
    const int lane = tid & 63;
    const int wave = tid >> 6;
    const int col  = blockIdx.x * 4 + wave;

    if (tid < NL * NQ) {
        float phi = w[3 * tid], th = w[3 * tid + 1], om = w[3 * tid + 2];
        float ch = cosf(0.5f * th), sh = sinf(0.5f * th);
        float ap = -0.5f * (phi + om), am = -0.5f * (phi - om);
        float epr = cosf(ap), epi = sinf(ap);
        float emr = cosf(am), emi = sinf(am);
        Uc[tid][0] =  epr * ch;  // u00r
        Uc[tid][1] =  epi * ch;  // u00i
        Uc[tid][2] = -emr * sh;  // u01r
        Uc[tid][3] =  emi * sh;  // u01i
        Uc[tid][4] =  emr * sh;  // u10r
        Uc[tid][5] =  emi * sh;  // u10i
        Uc[tid][6] =  epr * ch;  // u11r
        Uc[tid][7] = -epi * ch;  // u11i
    }
    __syncthreads();

    float re = (lane == col) ? 1.f : 0.f;
    float im = 0.f;

    #pragma unroll
    for (int l = 0; l < NL; ++l) {
        #pragma unroll
        for (int j = 0; j < NQ; ++j) {
            const int g = l * NQ + j;
            const int m = 1 << (5 - j);
            float4 uA = *(const float4*)&Uc[g][0];  // u00r u00i u01r u01i
            float4 uB = *(const float4*)&Uc[g][4];  // u10r u10i u11r u11i
            float pr = __shfl_xor(re, m);
            float pi = __shfl_xor(im, m);
            const bool hi = (lane & m) != 0;
            float Ar = hi ? uB.z : uA.x;
            float Ai = hi ? uB.w : uA.y;
            float Br = hi ? uB.x : uA.z;
            float Bi = hi ? uB.y : uA.w;
            float nr = Ar * re - Ai * im + Br * pr - Bi * pi;
            float ni = Ar * im + Ai * re + Br * pi + Bi * pr;
            re = nr; im = ni;
        }
        // fused CNOT-ring permutation: new[k] = old[src(k)]
        const int r = l % (NQ - 1) + 1;
        int src = lane;
        #pragma unroll
        for (int jj = NQ - 1; jj >= 0; --jj) {
            int cm = 1 << (5 - jj);
            int tm = 1 << (5 - ((jj + r) % NQ));
            src = (src & cm) ? (src ^ tm) : src;
        }
        re = __shfl(re, src);
        im = __shfl(im, src);
    }

    _Float16 hr = (_Float16)re, hi16 = (_Float16)im;
    Cu[lane * 64 + col]        = __builtin_bit_cast(unsigned short, hr);
    Cu[4096 + lane * 64 + col] = __builtin_bit_cast(unsigned short, hi16);
}

// ---------------------------------------------------------------------------
// Kernel 2: MFMA matvec + factored sign-sum epilogue.
// Per wave: 64 samples. psi (f16) per lane -> LDS (stride 36 dwords).
// grp loop ROLLED (pragma unroll 1) to cap live acc regs at one grp (32)
// -> VGPR budget ~128 -> 4 waves/SIMD.
// Epilogue: signs factor by index class: bit5,bit4 <- t (compile-time),
// bit3,bit2 <- g (per-lane XOR of the shared total P), bit1,bit0 <- i
// (column partials). 88 VALU/grp instead of 144 — same arithmetic.
// ---------------------------------------------------------------------------
__global__ __launch_bounds__(256) void qexp_mfma(const float* __restrict__ x,
                                                 const unsigned* __restrict__ C,
                                                 float* __restrict__ out,
                                                 int batch) {
    __shared__ __align__(16) unsigned Psi[256 * 36];  // 36 KB, 144 B/row
    const int tid  = threadIdx.x;
    const int lane = tid & 63;
    const int wave = tid >> 6;
    const int n    = lane & 15;
    const int g    = lane >> 4;
    const int sbase = blockIdx.x * 256 + wave * 64;

    // ---- persistent A-frags: C matrix, 16 frags (4 ktiles x 2 ksteps x Re/Im)
    half8 Ar[4][2], Ai[4][2];
    #pragma unroll
    for (int t = 0; t < 4; ++t)
        #pragma unroll
        for (int s = 0; s < 2; ++s) {
            int dw = (t * 16 + n) * 32 + s * 16 + g * 4;
            Ar[t][s] = __builtin_bit_cast(half8, *(const int4*)(C + dw));
            Ai[t][s] = __builtin_bit_cast(half8, *(const int4*)(C + 2048 + dw));
        }

    // ---- psi for sample sbase+lane, f16-packed into LDS row tid
    {
        const float2* xp = (const float2*)(x + (size_t)(sbase + lane) * NQ);
        float2 x01 = xp[0], x23 = xp[1], x45 = xp[2];
        float xa[6] = {x01.x, x01.y, x23.x, x23.y, x45.x, x45.y};
        float cs[6], sn[6];
        #pragma unroll
        for (int j = 0; j < 6; ++j) {
            float a = 1.57079632679489662f * xa[j];
            __sincosf(a, &sn[j], &cs[j]);
        }
        float a00 = cs[0] * cs[1], a01 = cs[0] * sn[1];
        float a10 = sn[0] * cs[1], a11 = sn[0] * sn[1];
        float hi[8] = {a00 * cs[2], a00 * sn[2], a01 * cs[2], a01 * sn[2],
                       a10 * cs[2], a10 * sn[2], a11 * cs[2], a11 * sn[2]};
        float b00 = cs[3] * cs[4], b01 = cs[3] * sn[4];
        float b10 = sn[3] * cs[4], b11 = sn[3] * sn[4];
        float lo[8] = {b00 * cs[5], b00 * sn[5], b01 * cs[5], b01 * sn[5],
                       b10 * cs[5], b10 * sn[5], b11 * cs[5], b11 * sn[5]};
        const int rowbase = tid * 36;
        #pragma unroll
        for (int c = 0; c < 8; ++c) {
            float h = hi[c];
            int4 d;
            d.x = __builtin_bit_cast(int, __builtin_amdgcn_cvt_pkrtz(h * lo[0], h * lo[1]));
            d.y = __builtin_bit_cast(int, __builtin_amdgcn_cvt_pkrtz(h * lo[2], h * lo[3]));
            d.z = __builtin_bit_cast(int, __builtin_amdgcn_cvt_pkrtz(h * lo[4], h * lo[5]));
            d.w = __builtin_bit_cast(int, __builtin_amdgcn_cvt_pkrtz(h * lo[6], h * lo[7]));
            *(int4*)(&Psi[rowbase + c * 4]) = d;
        }
    }
    __syncthreads();

    const unsigned m2 = (unsigned)(g >> 1) << 31;   // k_out bit3 sign (j=2)
    const unsigned m3 = (unsigned)(g & 1) << 31;    // k_out bit2 sign (j=3)

    #pragma unroll 1
    for (int grp = 0; grp < 4; ++grp) {
        f32x4 accr[4], acci[4];
        #pragma unroll
        for (int t = 0; t < 4; ++t) { accr[t] = (f32x4)0.f; acci[t] = (f32x4)0.f; }

        #pragma unroll
        for (int s = 0; s < 2; ++s) {
            int bd = (wave * 64 + grp * 16 + n) * 36 + s * 16 + g * 4;
            half8 B = __builtin_bit_cast(half8, *(const int4*)(&Psi[bd]));
            #pragma unroll
            for (int t = 0; t < 4; ++t) {
                accr[t] = __builtin_amdgcn_mfma_f32_16x16x32_f16(Ar[t][s], B, accr[t], 0, 0, 0);
                acci[t] = __builtin_amdgcn_mfma_f32_16x16x32_f16(Ai[t][s], B, acci[t], 0, 0, 0);
            }
        }

        // factored sign-sums: k_out = t*16 + g*4 + i
        float s01[4], s23[4], a02[4], T[4];
        #pragma unroll
        for (int t = 0; t < 4; ++t) {
            float p0 = fmaf(accr[t][0], accr[t][0], acci[t][0] * acci[t][0]);
            float p1 = fmaf(accr[t][1], accr[t][1], acci[t][1] * acci[t][1]);
            float p2 = fmaf(accr[t][2], accr[t][2], acci[t][2] * acci[t][2]);
            float p3 = fmaf(accr[t][3], accr[t][3], acci[t][3] * acci[t][3]);
            s01[t] = p0 + p1;
            s23[t] = p2 + p3;
            a02[t] = p0 + p2;
            T[t]   = s01[t] + s23[t];
        }
        float u = T[0] + T[1], v = T[2] + T[3];
        float P = u + v;
        float o0 = u - v;                      // j=0: sign = bit5 = t&2
        float w = T[0] + T[2];
        float o1 = fmaf(2.f, w, -P);           // j=1: sign = bit4 = t&1
        float S01 = (s01[0] + s01[1]) + (s01[2] + s01[3]);
        float o4 = fmaf(2.f, S01, -P);         // j=4: sign = bit1 = i&2
        float Sa = (a02[0] + a02[1]) + (a02[2] + a02[3]);
        float o5 = fmaf(2.f, Sa, -P);          // j=5: sign = bit0 = i&1
        float o2 = __builtin_bit_cast(float, __builtin_bit_cast(unsigned, P) ^ m2);
        float o3 = __builtin_bit_cast(float, __builtin_bit_cast(unsigned, P) ^ m3);

        // fold the 4 k-groups (lanes n, n+16, n+32, n+48)
        o0 += __shfl_xor(o0, 16); o0 += __shfl_xor(o0, 32);
        o1 += __shfl_xor(o1, 16); o1 += __shfl_xor(o1, 32);
        o2 += __shfl_xor(o2, 16); o2 += __shfl_xor(o2, 32);
        o3 += __shfl_xor(o3, 16); o3 += __shfl_xor(o3, 32);
        o4 += __shfl_xor(o4, 16); o4 += __shfl_xor(o4, 32);
        o5 += __shfl_xor(o5, 16); o5 += __shfl_xor(o5, 32);

        int sample = sbase + grp * 16 + n;
        float2* op = (float2*)(out + (size_t)sample * 6);
        if (g == 0)      { op[0] = make_float2(o0, o1); op[1] = make_float2(o2, o3); }
        else if (g == 1) { op[2] = make_float2(o4, o5); }
    }
}

extern "C" void kernel_launch(void* const* d_in, const int* in_sizes, int n_in,
                              void* d_out, int out_size, void* d_ws, size_t ws_size,
                              hipStream_t stream) {
    const float* x = (const float*)d_in[0];
    const float* w = (const float*)d_in[1];
    unsigned* C = (unsigned*)d_ws;   // 4096 dwords = 16 KB (f16-packed Re|Im)
    float* out = (float*)d_out;
    const int batch = in_sizes[0] / NQ;

    build_C_kernel<<<16, 256, 0, stream>>>(w, (unsigned short*)C);
    const int blocks = (batch + 255) / 256;   // 1024 blocks x 256 threads
    qexp_mfma<<<blocks, 256, 0, stream>>>(x, C, out, batch);
}